// Round 15
// baseline (106.065 us; speedup 1.0000x reference)
//
#include <hip/hip_runtime.h>

// SSM DPLR kernel: K[h,l] = 2*Re(C_h . dA_h^l . dB_h), dA = diag(g) + q r^T.
// R18 (= R17 - idmk hoist): R17 was neutral vs R16 (step-halving gained 0) ->
// per-step cost doubled -> spill signature (R7/R12/R13 pattern): Mk[16]+
// idmk[16]+hoisted-broadcasts ~135 regs > 128 arch-VGPR ceiling; wave0's
// solve window also carried the 32-reg idmk hoist. Fix: inline cinv in
// buildM (R10/R11-proven), halving array pressure. Nothing else changes.
//   - chain A (waves 0..3): C (M128)^i -> even rows, 15 steps
//   - chain B (waves 4..7): (C M64)(M128)^i -> odd rows, 16 steps + rebuild
//   - independent sync domains; replicated reduce into per-wave private cbuf
//   - 512 threads (8 waves), grid 256, amdgpu_waves_per_eu(2,2)
//   - wave0: tau128-solve + dual Horner; wave1: sigma-solve + X rebuild

#define LL 2048

struct C2 { float re, im; };

__device__ __forceinline__ C2 cmul(C2 a, C2 b){ return {a.re*b.re - a.im*b.im, a.re*b.im + a.im*b.re}; }
__device__ __forceinline__ C2 cadd(C2 a, C2 b){ return {a.re+b.re, a.im+b.im}; }
__device__ __forceinline__ C2 csub(C2 a, C2 b){ return {a.re-b.re, a.im-b.im}; }
__device__ __forceinline__ C2 cinv(C2 a){ float s=1.0f/(a.re*a.re+a.im*a.im); return {a.re*s, -a.im*s}; }
__device__ __forceinline__ C2 cscale(float s, C2 a){ return {s*a.re, s*a.im}; }
__device__ __forceinline__ C2 ld2(float2 v){ return {v.x, v.y}; }
__device__ __forceinline__ float2 st2(C2 v){ return make_float2(v.re, v.im); }

template<int CTRL>
__device__ __forceinline__ float dpp_add(float x){
  int t = __builtin_amdgcn_update_dpp(0, __float_as_int(x), CTRL, 0xF, 0xF, true);
  return x + __int_as_float(t);
}
// lane 63 ends with the full 64-lane sum
__device__ __forceinline__ float wave_sum63(float x){
  x = dpp_add<0xB1>(x);   // quad_perm xor1
  x = dpp_add<0x4E>(x);   // quad_perm xor2
  x = dpp_add<0x124>(x);  // row_ror:4
  x = dpp_add<0x128>(x);  // row_ror:8
  x = dpp_add<0x142>(x);  // row_bcast:15
  x = dpp_add<0x143>(x);  // row_bcast:31
  return x;
}
__device__ __forceinline__ float bcast63(float x){
  return __int_as_float(__builtin_amdgcn_readlane(__float_as_int(x), 63));
}
__device__ __forceinline__ float rdlane(float v, int l){
  return __int_as_float(__builtin_amdgcn_readlane(__float_as_int(v), l));
}
// D[m] = S[m-1], lane0 <- 0   (wave_shr:1 = 0x138)
__device__ __forceinline__ float shr1(float x){
  return __int_as_float(__builtin_amdgcn_update_dpp(0, __float_as_int(x), 0x138, 0xF, 0xF, true));
}
// insert scalar s (SGPR, from readlane) into lane 0 of v: v_cndmask
__device__ __forceinline__ float ins0(float v, float s, int lane){
  return (lane == 0) ? s : v;
}

// 2-wide triangular-Toeplitz solve (length 64): v_j = rhs_j + sum_{i<j} w_{j-1-i} v_i.
__device__ __forceinline__ void tri_solve64(const C2 wl, C2 va, const int lane,
                                            float& so_re, float& so_im)
{
    C2 wsh = { shr1(wl.re), shr1(wl.im) };      // w_{m-1}, lane0 = 0
    const float w0r = rdlane(wl.re, 0);
    const float w0i = rdlane(wl.im, 0);
    so_re = 0.0f; so_im = 0.0f;
    for (int j = 0; j < 64; j += 2) {
        const float s0r = rdlane(va.re, j);
        const float s0i = rdlane(va.im, j);
        const float v1r = rdlane(va.re, j + 1);
        const float v1i = rdlane(va.im, j + 1);
        const float s1r = v1r + (w0r*s0r - w0i*s0i);
        const float s1i = v1i + (w0r*s0i + w0i*s0r);
        if (lane == j)     { so_re = s0r; so_im = s0i; }
        if (lane == j + 1) { so_re = s1r; so_im = s1i; }
        const C2 wsh1 = { shr1(wsh.re), shr1(wsh.im) };   // w_{m-2-j}
        va.re += wsh.re*s0r - wsh.im*s0i;
        va.im += wsh.re*s0i + wsh.im*s0r;
        va.re += wsh1.re*s1r - wsh1.im*s1i;
        va.im += wsh1.re*s1i + wsh1.im*s1r;
        wsh.re = shr1(wsh1.re);
        wsh.im = shr1(wsh1.im);
    }
}

// 2-wide extended solve (length 128): state split lo (j=0..63) / hi (j=64..127).
// On return: tlo lane j = tau_j, thi lane c = tau_{64+c}.   (R6b-verified)
__device__ __forceinline__ void tri_solve128(const C2 wlo, const C2 whi, const int lane,
                                             C2& tlo, C2& thi)
{
    C2 valo = wlo, vahi = whi;                  // rhs = w (tau solve)
    C2 wsl = { shr1(wlo.re), shr1(wlo.im) };    // w_{m-1}
    C2 wsh;                                     // w_{63+m'}
    {
        const float br = rdlane(wlo.re, 63), bi = rdlane(wlo.im, 63);
        wsh.re = ins0(shr1(whi.re), br, lane);
        wsh.im = ins0(shr1(whi.im), bi, lane);
    }
    const float w0r = rdlane(wlo.re, 0);
    const float w0i = rdlane(wlo.im, 0);
    tlo = {0,0}; thi = {0,0};
    // lo region: sources j = 0..63
    for (int j = 0; j < 64; j += 2) {
        const float s0r = rdlane(valo.re, j);
        const float s0i = rdlane(valo.im, j);
        const float v1r = rdlane(valo.re, j + 1);
        const float v1i = rdlane(valo.im, j + 1);
        const float s1r = v1r + (w0r*s0r - w0i*s0i);
        const float s1i = v1i + (w0r*s0i + w0i*s0r);
        if (lane == j)     { tlo.re = s0r; tlo.im = s0i; }
        if (lane == j + 1) { tlo.re = s1r; tlo.im = s1i; }
        const C2 wsl1 = { shr1(wsl.re), shr1(wsl.im) };           // w_{m-2-j}
        C2 wsh1;
        {
            const float br = rdlane(wsl.re, 63), bi = rdlane(wsl.im, 63);  // w_{62-j}
            wsh1.re = ins0(shr1(wsh.re), br, lane);
            wsh1.im = ins0(shr1(wsh.im), bi, lane);
        }
        valo.re += wsl.re*s0r - wsl.im*s0i + wsl1.re*s1r - wsl1.im*s1i;
        valo.im += wsl.re*s0i + wsl.im*s0r + wsl1.re*s1i + wsl1.im*s1r;
        vahi.re += wsh.re*s0r - wsh.im*s0i + wsh1.re*s1r - wsh1.im*s1i;
        vahi.im += wsh.re*s0i + wsh.im*s0r + wsh1.re*s1i + wsh1.im*s1r;
        wsl.re = shr1(wsl1.re); wsl.im = shr1(wsl1.im);
        {
            const float br = rdlane(wsl1.re, 63), bi = rdlane(wsl1.im, 63); // w_{61-j}
            wsh.re = ins0(shr1(wsh1.re), br, lane);
            wsh.im = ins0(shr1(wsh1.im), bi, lane);
        }
    }
    // hi region: sources j = 64..127; lo coefficients exhausted, shift-ins are 0.
    for (int j = 64; j < 128; j += 2) {
        const int jr = j - 64;
        const float s0r = rdlane(vahi.re, jr);
        const float s0i = rdlane(vahi.im, jr);
        const float v1r = rdlane(vahi.re, jr + 1);
        const float v1i = rdlane(vahi.im, jr + 1);
        const float s1r = v1r + (w0r*s0r - w0i*s0i);
        const float s1i = v1i + (w0r*s0i + w0i*s0r);
        if (lane == jr)     { thi.re = s0r; thi.im = s0i; }
        if (lane == jr + 1) { thi.re = s1r; thi.im = s1i; }
        const C2 wsh1 = { shr1(wsh.re), shr1(wsh.im) };
        vahi.re += wsh.re*s0r - wsh.im*s0i + wsh1.re*s1r - wsh1.im*s1i;
        vahi.im += wsh.re*s0i + wsh.im*s0r + wsh1.re*s1i + wsh1.im*s1r;
        wsh.re = shr1(wsh1.re);
        wsh.im = shr1(wsh1.im);
    }
}

__global__ __launch_bounds__(512)
__attribute__((amdgpu_waves_per_eu(2, 2)))
void ssm_dplr_kernel(
    const float* __restrict__ A_real, const float* __restrict__ A_imag,
    const float* __restrict__ B_real, const float* __restrict__ B_imag,
    const float* __restrict__ P_real, const float* __restrict__ P_imag,
    const float* __restrict__ C_real, const float* __restrict__ C_imag,
    const float* __restrict__ log_dt, float* __restrict__ out)
{
    const int h    = blockIdx.x;
    const int t    = threadIdx.x;
    const int lane = t & 63;
    const int wid  = t >> 6;         // wave 0..7

    extern __shared__ char sm[];
    float2* Abuf = (float2*)sm;               // 64x64: G (powers), later X  [32 KB]
    float2* Cs   = (float2*)(sm + 32768);     // 32x64 Y rows                [16 KB]
    // transpose-sum partials alias Cs (dead at that phase):
    float2* tw   = Cs;                        // 8x64
    float2* ta   = Cs + 512;                  // 8x64
    float2* te   = Cs + 1024;                 // 8x64
    // persistent smalls @49152 (live through the chain):
    float2* gA   = (float2*)(sm + 49152);
    float2* qA   = gA + 64;
    float2* g64A = gA + 128;
    float2* TgA  = gA + 192;   // T64(g)
    float2* TpA  = gA + 256;   // T64'(g)
    float2* T1gA = gA + 320;   // T128(g)
    float2* T1pA = gA + 384;   // T128'(g)
    // overlay @52736: transient smalls during setup, chain sync area later
    char* ovl = sm + 52736;
    float2* rqA  = (float2*)ovl;       // rq            (dead after t-sums)
    float2* rxA  = rqA + 64;           // r x0
    float2* reA  = rqA + 128;          // rq g64
    float2* wvA  = rqA + 192;          // w_0..63       (dead after serial win.)
    float2* avA  = rqA + 256;          // a_0..63
    float2* weA  = rqA + 320;          // w_64..127
    // chain-phase occupants of the same bytes:
    float2* cbufAll = (float2*)ovl;            // 8 x 64 per-wave private  [4 KB]
    float2* prtC    = (float2*)(sm + 56832);   // [2][8][64] partials      [8 KB]
    int*    cntA    = (int*)(sm + 65024);      // 32 step counters chain A
    int*    cntB    = cntA + 32;               // 32 step counters chain B
    // LDS total: 65280 B

    // ---------------- setup (every wave redundantly, per-lane n = lane) ----------------
    const int idx = h * 64 + lane;
    const float dt = expf(log_dt[h]);
    const float c  = 0.5f * dt;

    const C2 lam = { -A_real[idx], -A_imag[idx] };
    const C2 p   = {  P_real[idx],  P_imag[idx] };
    const C2 Bv  = {  B_real[idx],  B_imag[idx] };
    const C2 Cv  = {  C_real[idx],  C_imag[idx] };
    const C2 pc  = { p.re, -p.im };

    const C2 d = cinv(C2{ 1.0f - c*lam.re, -c*lam.im });
    const C2 g = cmul(d, C2{ 1.0f + c*lam.re, c*lam.im });   // diag of dA

    // Sherman-Morrison scalars via DPP wave sums
    C2 sv = cscale(p.re*p.re + p.im*p.im, d);
    C2 uv = cmul(cmul(d, pc), Bv);
    sv.re = bcast63(wave_sum63(sv.re)); sv.im = bcast63(wave_sum63(sv.im));
    uv.re = bcast63(wave_sum63(uv.re)); uv.im = bcast63(wave_sum63(uv.im));

    const C2 beta  = cscale(c, cinv(C2{ 1.0f + c*sv.re, c*sv.im }));
    const C2 bs    = cmul(beta, sv);
    const C2 gamma = { -c*(1.0f - bs.re), c*bs.im };

    const C2 q  = cmul(d, p);
    const C2 r  = cmul(pc, csub(gamma, cmul(beta, g)));
    const C2 x0 = cscale(dt, csub(cmul(d, Bv), cmul(cmul(beta, uv), q)));  // dB

    // power chain
    const C2 g2  = cmul(g,  g);
    const C2 g4  = cmul(g2, g2);
    const C2 g8  = cmul(g4, g4);
    const C2 g16 = cmul(g8, g8);
    const C2 g32 = cmul(g16,g16);
    const C2 g64 = cmul(g32,g32);

    if (wid == 0) {
        const C2 rq = cmul(r, q);
        gA[lane]   = st2(g);
        qA[lane]   = st2(q);
        g64A[lane] = st2(g64);
        rqA[lane]  = st2(rq);
        rxA[lane]  = st2(cmul(r, x0));
        reA[lane]  = st2(cmul(rq, g64));
    }
    __syncthreads();

    // ---------------- G-gen: G[j][n] = g_n^j, rows j in [8w, 8w+8) ----------------
    {
        C2 cur = {1.0f, 0.0f};
        if (wid & 1) cur = g8;
        if (wid & 2) cur = cmul(cur, g16);
        if (wid & 4) cur = cmul(cur, g32);          // g^(8*wid)
        #pragma unroll
        for (int jj = 0; jj < 8; ++jj) {
            const int j = 8*wid + jj;
            Abuf[j*64 + ((lane + j) & 63)] = st2(cur);   // rotated columns
            cur = cmul(cur, g);
        }
    }
    __syncthreads();

    // ---------------- w_j, a_j, we_j (=w_{64+j}) via transpose-sum (lane = j) ---------
    {
        C2 accw = {0,0}, acca = {0,0}, acce = {0,0};
        #pragma unroll
        for (int kk = 0; kk < 8; ++kk) {
            const int n = 8*wid + kk;
            const C2 Gv = ld2(Abuf[lane*64 + ((n + lane) & 63)]);
            const C2 fq = ld2(rqA[n]);      // uniform
            const C2 fx = ld2(rxA[n]);      // uniform
            const C2 fe = ld2(reA[n]);      // uniform
            accw = cadd(accw, cmul(Gv, fq));
            acca = cadd(acca, cmul(Gv, fx));
            acce = cadd(acce, cmul(Gv, fe));
        }
        tw[wid*64 + lane] = st2(accw);
        ta[wid*64 + lane] = st2(acca);
        te[wid*64 + lane] = st2(acce);
    }
    __syncthreads();
    if (t < 64) {
        C2 sw = {0,0}, sa = {0,0}, se = {0,0};
        #pragma unroll
        for (int w2 = 0; w2 < 8; ++w2) {
            sw = cadd(sw, ld2(tw[w2*64 + t]));
            sa = cadd(sa, ld2(ta[w2*64 + t]));
            se = cadd(se, ld2(te[w2*64 + t]));
        }
        wvA[t] = st2(sw);
        avA[t] = st2(sa);
        weA[t] = st2(se);
    }
    __syncthreads();

    // ---------------- serial window ----------------
    // wave0: tau128-solve + dual Horner -> T64/T64'/T128/T128'
    // wave1: sigma-solve + X rebuild into Abuf (G is dead now)
    const bool isB = (wid >= 4);
    const int  wg  = wid & 3;              // row-group index 0..3 within chain
    if (wid == 0) {
        C2 tlo, thi;
        tri_solve128(ld2(wvA[lane]), ld2(weA[lane]), lane, tlo, thi);
        // P-Horner over tau_0..62 ; Q-Horner over tau_63..126 (interleaved chains)
        C2 pp = { rdlane(tlo.re, 0),  rdlane(tlo.im, 0)  };
        C2 dd = {0,0};
        C2 qq = { rdlane(tlo.re, 63), rdlane(tlo.im, 63) };   // tau_63
        C2 qd = {0,0};
        for (int i = 1; i <= 63; ++i) {
            if (i <= 62) {
                const C2 ti = { rdlane(tlo.re, i), rdlane(tlo.im, i) };
                dd = cadd(cmul(dd, g), pp);
                pp = cadd(cmul(pp, g), ti);
            }
            const C2 tq = { rdlane(thi.re, i-1), rdlane(thi.im, i-1) };  // tau_{63+i}
            qd = cadd(cmul(qd, g), qq);
            qq = cadd(cmul(qq, g), tq);
        }
        const C2 T64v = cmul(g, pp);              // T64(g)
        const C2 T64d = cadd(pp, cmul(g, dd));    // T64'(g)
        // T128(z) = z^64 T64(z) + z Q(z);  T128' = 64 z^63 T64 + z^64 T64' + Q + z Q'
        const C2 g63h  = cmul(g64, cinv(g));
        const C2 T128v = cadd(cmul(g64, T64v), cmul(g, qq));
        const C2 T128d = cadd(cadd(cscale(64.0f, cmul(g63h, T64v)), cmul(g64, T64d)),
                              cadd(qq, cmul(g, qd)));
        TgA[lane]  = st2(T64v);
        TpA[lane]  = st2(T64d);
        T1gA[lane] = st2(T128v);
        T1pA[lane] = st2(T128d);
    } else if (wid == 1) {
        float sg_re, sg_im;
        tri_solve64(ld2(wvA[lane]), ld2(avA[lane]), lane, sg_re, sg_im);   // sigma
        // X_0 = dB; X_{j+1} = g.*X_j + sigma_j * q
        C2 x = x0;
        for (int j = 0; j < 64; ++j) {
            Abuf[j*64 + ((lane + j) & 63)] = st2(x);
            const float sjr = rdlane(sg_re, j);
            const float sji = rdlane(sg_im, j);
            const float nr = g.re*x.re - g.im*x.im + sjr*q.re - sji*q.im;
            const float ni = g.re*x.im + g.im*x.re + sjr*q.im + sji*q.re;
            x.re = nr; x.im = ni;
        }
    }
    __syncthreads();   // transient smalls die here; overlay switches to sync area

    // ---------------- M build (regs, rows k = 16wg..16wg+15) + sync init ----------
    // M_t[k][m] = d_km g^t_k + q_k r_m [ (g^t_k - g^t_m) + (T_t(g_k)-T_t(g_m)) ] / (g_k - g_m)
    // M_t[k][k] = g^t_k + q_k r_k ( t g_k^{t-1} + T_t'(g_k) )
    // cinv computed INLINE (no idmk hoist -> Mk[16] is the only array; ~77 regs)
    C2 Mk[16];
    auto buildM = [&](bool p128){
        const C2 gt   = p128 ? cmul(g64, g64) : g64;                    // g^t (lane m)
        const C2 Ttm  = p128 ? ld2(T1gA[lane]) : ld2(TgA[lane]);
        const C2 Tp   = p128 ? ld2(T1pA[lane]) : ld2(TpA[lane]);
        const C2 g63  = cmul(g64, cinv(g));
        const C2 gtm1 = p128 ? cmul(g64, g63) : g63;                    // g^{t-1}
        const C2 S    = cmul(r, cadd(cscale(p128 ? 128.0f : 64.0f, gtm1), Tp));
        const C2 diagv = cadd(gt, cmul(q, S));    // value for M[lane][lane]
        #pragma unroll
        for (int kk = 0; kk < 16; ++kk) {
            const int k = 16*wg + kk;
            const C2 qn   = ld2(qA[k]);            // uniform reads
            const C2 g64n = ld2(g64A[k]);
            const C2 gtn  = p128 ? cmul(g64n, g64n) : g64n;
            const C2 Ttn  = p128 ? ld2(T1gA[k]) : ld2(TgA[k]);
            const C2 idm  = cinv(csub(ld2(gA[k]), g));       // inline, k==lane deselected
            const C2 num  = cmul(r, cadd(csub(gtn, gt), csub(Ttn, Ttm)));
            const C2 off  = cmul(cmul(qn, num), idm);
            const bool isd = (lane == k);
            Mk[kk].re = isd ? diagv.re : off.re;
            Mk[kk].im = isd ? diagv.im : off.im;
        }
    };
    if (!isB) buildM(true);            // chain A: M128
    else      buildM(false);           // chain B: M64 (seed), rebuilt after step 0
    if (wid == 0) Cs[lane] = st2(Cv);  // output row 0 = C
    if (wid == 2) {                    // zero both counter arrays
        if (lane < 32) cntA[lane] = 0;
        else           cntB[lane - 32] = 0;
    }
    __syncthreads();                   // M regs + counters + Cs[0] visible

    // ---------------- dual flag-synced chains (no barriers, no cross-chain waits) ----
    {
        float2* cb = cbufAll + wid*64;             // per-wave PRIVATE broadcast buffer
        const float4* cb4 = (const float4*)cb;
        volatile int* vcnt = isB ? (volatile int*)cntB : (volatile int*)cntA;
        int* cnt = isB ? cntB : cntA;
        const int base = isB ? 4 : 0;              // prt slot base for this chain
        cb[lane] = st2(Cv);                        // step input C_0 = C

        const int s0 = isB ? 0 : 1;                // B has an extra seed step
        for (int s = s0; s <= 15; ++s) {
            const int buf = s & 1;
            // produce: this wave's 16-row slice of y . M
            float ar = 0.0f, ai = 0.0f;
            #pragma unroll
            for (int kp = 0; kp < 8; ++kp) {
                const float4 cc = cb4[8*wg + kp];  // uniform: c_{16wg+2kp}, c_{16wg+2kp+1}
                ar += cc.x*Mk[2*kp].re   - cc.y*Mk[2*kp].im;
                ai += cc.x*Mk[2*kp].im   + cc.y*Mk[2*kp].re;
                ar += cc.z*Mk[2*kp+1].re - cc.w*Mk[2*kp+1].im;
                ai += cc.z*Mk[2*kp+1].im + cc.w*Mk[2*kp+1].re;
            }
            prtC[buf*512 + (base + wg)*64 + lane] = make_float2(ar, ai);
            __threadfence_block();
            if (lane == 0) atomicAdd(&cnt[s], 1);
            while (vcnt[s] < 4) { }
            __asm__ volatile("" ::: "memory");
            // replicated reduce: every wave builds the full new vector
            C2 nc = {0,0};
            #pragma unroll
            for (int w2 = 0; w2 < 4; ++w2) {
                const float2 pv = prtC[buf*512 + (base + w2)*64 + lane];
                nc.re += pv.x; nc.im += pv.y;
            }
            cb[lane] = st2(nc);                    // own copy for next step (in-order DS)
            if (!isB) {
                if (wid == 0) Cs[(2*s)*64 + lane] = st2(nc);       // even row 2s
            } else {
                if (wid == 4) Cs[(2*s + 1)*64 + lane] = st2(nc);   // odd row 2s+1
                if (s == 0) buildM(true);          // rebuild Mk as M128 after seed
            }
        }
    }
    __syncthreads();

    // ---------------- output: rows r = 4*wid + rr ----------------
    {
        float accK[4] = {0.0f, 0.0f, 0.0f, 0.0f};
        #pragma unroll 8
        for (int n = 0; n < 64; ++n) {
            const float2 xv = Abuf[lane*64 + ((n + lane) & 63)];
            #pragma unroll
            for (int rr = 0; rr < 4; ++rr) {
                const float2 cv = Cs[(4*wid + rr)*64 + n];   // uniform
                accK[rr] += cv.x*xv.x - cv.y*xv.y;
            }
        }
        float* outh = out + h * LL;
        #pragma unroll
        for (int rr = 0; rr < 4; ++rr) {
            outh[(4*wid + rr)*64 + lane] = 2.0f * accK[rr];
        }
    }
}

extern "C" void kernel_launch(void* const* d_in, const int* in_sizes, int n_in,
                              void* d_out, int out_size, void* d_ws, size_t ws_size,
                              hipStream_t stream) {
    const float* A_real = (const float*)d_in[0];
    const float* A_imag = (const float*)d_in[1];
    const float* B_real = (const float*)d_in[2];
    const float* B_imag = (const float*)d_in[3];
    const float* P_real = (const float*)d_in[4];
    const float* P_imag = (const float*)d_in[5];
    const float* C_real = (const float*)d_in[6];
    const float* C_imag = (const float*)d_in[7];
    const float* log_dt = (const float*)d_in[8];
    float* out = (float*)d_out;

    const size_t lds = 65280;
    ssm_dplr_kernel<<<256, 512, lds, stream>>>(
        A_real, A_imag, B_real, B_imag, P_real, P_imag,
        C_real, C_imag, log_dt, out);
}

// Round 16
// 101.837 us; speedup vs baseline: 1.0415x; 1.0415x over previous
//
#include <hip/hip_runtime.h>

// SSM DPLR kernel: K[h,l] = 2*Re(C_h . dA_h^l . dB_h), dA = diag(g) + q r^T.
// R19 (= R16 + replicated reduce): R16 (101.9us, best) had TWO sync hops per
// chain step (atomic+spin for partials, then flag hop through wave0's reduce).
// R17/R18 proved step-halving is value-neutral -> per-step SYNC dominates.
// R19 keeps R16's exact structure (single M64 chain, 31 steps, 8 waves,
// Mk[8]+idmk[8] per wave) and removes the flag hop: every wave reduces the 8
// partials itself and writes its OWN private cbuf for next step's uniform
// reads. One sync point per step. prt double-buffered [2][8][64]: a wave
// writes buffer b at step s+2 only after cnt[s+1]==8, which orders it after
// all waves' step-s reads of b (program order per wave) -> race-free, no flag.
//   - 512 threads (8 waves), grid 256, amdgpu_waves_per_eu(2,2)
//   - wave0: tau-solve + Horner(T64,T64'); wave1: sigma-solve + X rebuild
//   - all Mk/idmk indexing compile-time; diag via select (R10)

#define LL 2048

struct C2 { float re, im; };

__device__ __forceinline__ C2 cmul(C2 a, C2 b){ return {a.re*b.re - a.im*b.im, a.re*b.im + a.im*b.re}; }
__device__ __forceinline__ C2 cadd(C2 a, C2 b){ return {a.re+b.re, a.im+b.im}; }
__device__ __forceinline__ C2 csub(C2 a, C2 b){ return {a.re-b.re, a.im-b.im}; }
__device__ __forceinline__ C2 cinv(C2 a){ float s=1.0f/(a.re*a.re+a.im*a.im); return {a.re*s, -a.im*s}; }
__device__ __forceinline__ C2 cscale(float s, C2 a){ return {s*a.re, s*a.im}; }
__device__ __forceinline__ C2 ld2(float2 v){ return {v.x, v.y}; }
__device__ __forceinline__ float2 st2(C2 v){ return make_float2(v.re, v.im); }

template<int CTRL>
__device__ __forceinline__ float dpp_add(float x){
  int t = __builtin_amdgcn_update_dpp(0, __float_as_int(x), CTRL, 0xF, 0xF, true);
  return x + __int_as_float(t);
}
// lane 63 ends with the full 64-lane sum
__device__ __forceinline__ float wave_sum63(float x){
  x = dpp_add<0xB1>(x);   // quad_perm xor1
  x = dpp_add<0x4E>(x);   // quad_perm xor2
  x = dpp_add<0x124>(x);  // row_ror:4
  x = dpp_add<0x128>(x);  // row_ror:8
  x = dpp_add<0x142>(x);  // row_bcast:15
  x = dpp_add<0x143>(x);  // row_bcast:31
  return x;
}
__device__ __forceinline__ float bcast63(float x){
  return __int_as_float(__builtin_amdgcn_readlane(__float_as_int(x), 63));
}
__device__ __forceinline__ float rdlane(float v, int l){
  return __int_as_float(__builtin_amdgcn_readlane(__float_as_int(v), l));
}
// D[m] = S[m-1], lane0 <- 0   (wave_shr:1 = 0x138)
__device__ __forceinline__ float shr1(float x){
  return __int_as_float(__builtin_amdgcn_update_dpp(0, __float_as_int(x), 0x138, 0xF, 0xF, true));
}

// 2-wide triangular-Toeplitz solve (length 64): v_j = rhs_j + sum_{i<j} w_{j-1-i} v_i.
__device__ __forceinline__ void tri_solve64(const C2 wl, C2 va, const int lane,
                                            float& so_re, float& so_im)
{
    C2 wsh = { shr1(wl.re), shr1(wl.im) };      // w_{m-1}, lane0 = 0
    const float w0r = rdlane(wl.re, 0);
    const float w0i = rdlane(wl.im, 0);
    so_re = 0.0f; so_im = 0.0f;
    for (int j = 0; j < 64; j += 2) {
        const float s0r = rdlane(va.re, j);
        const float s0i = rdlane(va.im, j);
        const float v1r = rdlane(va.re, j + 1);
        const float v1i = rdlane(va.im, j + 1);
        const float s1r = v1r + (w0r*s0r - w0i*s0i);
        const float s1i = v1i + (w0r*s0i + w0i*s0r);
        if (lane == j)     { so_re = s0r; so_im = s0i; }
        if (lane == j + 1) { so_re = s1r; so_im = s1i; }
        const C2 wsh1 = { shr1(wsh.re), shr1(wsh.im) };   // w_{m-2-j}
        va.re += wsh.re*s0r - wsh.im*s0i;
        va.im += wsh.re*s0i + wsh.im*s0r;
        va.re += wsh1.re*s1r - wsh1.im*s1i;
        va.im += wsh1.re*s1i + wsh1.im*s1r;
        wsh.re = shr1(wsh1.re);
        wsh.im = shr1(wsh1.im);
    }
}

__global__ __launch_bounds__(512)
__attribute__((amdgpu_waves_per_eu(2, 2)))
void ssm_dplr_kernel(
    const float* __restrict__ A_real, const float* __restrict__ A_imag,
    const float* __restrict__ B_real, const float* __restrict__ B_imag,
    const float* __restrict__ P_real, const float* __restrict__ P_imag,
    const float* __restrict__ C_real, const float* __restrict__ C_imag,
    const float* __restrict__ log_dt, float* __restrict__ out)
{
    const int h    = blockIdx.x;
    const int t    = threadIdx.x;
    const int lane = t & 63;
    const int wid  = t >> 6;         // wave 0..7

    extern __shared__ char sm[];
    float2* Abuf = (float2*)sm;               // 64x64: G (powers), later X  [32 KB]
    float2* Cs   = (float2*)(sm + 32768);     // 32x64 Y rows                [16 KB]
    // transpose-sum partials alias Cs (dead at that phase):
    float2* tw   = Cs;                        // 8x64
    float2* ta   = Cs + 512;                  // 8x64
    // persistent smalls @49152 (live until M build done):
    float2* gA   = (float2*)(sm + 49152);
    float2* qA   = gA + 64;
    float2* g64A = gA + 128;
    float2* TgA  = gA + 192;   // T64(g)
    float2* TpA  = gA + 256;   // T64'(g)
    // transient smalls @51712 (dead after serial window):
    float2* rqA  = (float2*)(sm + 51712);
    float2* rxA  = rqA + 64;
    float2* wvA  = rqA + 128;  // w_0..63
    float2* avA  = rqA + 192;  // a_0..63
    // chain-phase occupants (cbufAll overlays the transient smalls):
    float2* cbufAll = (float2*)(sm + 51712);   // 8 x 64 per-wave private [4 KB]
    float2* prtC    = (float2*)(sm + 55808);   // [2][8][64] partials     [8 KB]
    int*    cntA    = (int*)(sm + 64000);      // 32 step counters        [128 B]
    // LDS total: 64128 B

    // ---------------- setup (every wave redundantly, per-lane n = lane) ----------------
    const int idx = h * 64 + lane;
    const float dt = expf(log_dt[h]);
    const float c  = 0.5f * dt;

    const C2 lam = { -A_real[idx], -A_imag[idx] };
    const C2 p   = {  P_real[idx],  P_imag[idx] };
    const C2 Bv  = {  B_real[idx],  B_imag[idx] };
    const C2 Cv  = {  C_real[idx],  C_imag[idx] };
    const C2 pc  = { p.re, -p.im };

    const C2 d = cinv(C2{ 1.0f - c*lam.re, -c*lam.im });
    const C2 g = cmul(d, C2{ 1.0f + c*lam.re, c*lam.im });   // diag of dA

    // Sherman-Morrison scalars via DPP wave sums
    C2 sv = cscale(p.re*p.re + p.im*p.im, d);
    C2 uv = cmul(cmul(d, pc), Bv);
    sv.re = bcast63(wave_sum63(sv.re)); sv.im = bcast63(wave_sum63(sv.im));
    uv.re = bcast63(wave_sum63(uv.re)); uv.im = bcast63(wave_sum63(uv.im));

    const C2 beta  = cscale(c, cinv(C2{ 1.0f + c*sv.re, c*sv.im }));
    const C2 bs    = cmul(beta, sv);
    const C2 gamma = { -c*(1.0f - bs.re), c*bs.im };

    const C2 q  = cmul(d, p);
    const C2 r  = cmul(pc, csub(gamma, cmul(beta, g)));
    const C2 x0 = cscale(dt, csub(cmul(d, Bv), cmul(cmul(beta, uv), q)));  // dB

    // power chain
    const C2 g2  = cmul(g,  g);
    const C2 g4  = cmul(g2, g2);
    const C2 g8  = cmul(g4, g4);
    const C2 g16 = cmul(g8, g8);
    const C2 g32 = cmul(g16,g16);
    const C2 g64 = cmul(g32,g32);

    if (wid == 0) {
        gA[lane]   = st2(g);
        qA[lane]   = st2(q);
        g64A[lane] = st2(g64);
        rqA[lane]  = st2(cmul(r, q));
        rxA[lane]  = st2(cmul(r, x0));
    }
    __syncthreads();

    // ---------------- G-gen: G[j][n] = g_n^j, rows j in [8w, 8w+8) ----------------
    {
        C2 cur = {1.0f, 0.0f};
        if (wid & 1) cur = g8;
        if (wid & 2) cur = cmul(cur, g16);
        if (wid & 4) cur = cmul(cur, g32);          // g^(8*wid)
        #pragma unroll
        for (int jj = 0; jj < 8; ++jj) {
            const int j = 8*wid + jj;
            Abuf[j*64 + ((lane + j) & 63)] = st2(cur);   // rotated columns
            cur = cmul(cur, g);
        }
    }
    __syncthreads();

    // ---------------- w_j, a_j via transpose-sum (lane = j) ----------------
    {
        C2 accw = {0,0}, acca = {0,0};
        #pragma unroll
        for (int kk = 0; kk < 8; ++kk) {
            const int n = 8*wid + kk;
            const C2 Gv = ld2(Abuf[lane*64 + ((n + lane) & 63)]);
            const C2 fq = ld2(rqA[n]);      // uniform
            const C2 fx = ld2(rxA[n]);      // uniform
            accw = cadd(accw, cmul(Gv, fq));
            acca = cadd(acca, cmul(Gv, fx));
        }
        tw[wid*64 + lane] = st2(accw);
        ta[wid*64 + lane] = st2(acca);
    }
    __syncthreads();
    if (t < 64) {
        C2 sw = {0,0}, sa = {0,0};
        #pragma unroll
        for (int w2 = 0; w2 < 8; ++w2) {
            sw = cadd(sw, ld2(tw[w2*64 + t]));
            sa = cadd(sa, ld2(ta[w2*64 + t]));
        }
        wvA[t] = st2(sw);
        avA[t] = st2(sa);
    }
    __syncthreads();

    // ---------------- serial window ----------------
    // all waves: division prep for their 8 M rows
    // wave0: tau-solve + Horner -> T64(g), T64'(g); seeds Cs[0] = C
    // wave1: sigma-solve + X rebuild into Abuf (G is dead now)
    // wave2: zero the chain step counters
    C2 idmk[8];
    #pragma unroll
    for (int kk = 0; kk < 8; ++kk) {
        idmk[kk] = cinv(csub(ld2(gA[8*wid + kk]), g));  // k==lane -> inf/NaN, deselected later
    }
    if (wid == 0) {
        Cs[lane] = st2(Cv);                     // output row 0
        const C2 wl = ld2(wvA[lane]);
        float tau_re, tau_im;
        tri_solve64(wl, wl, lane, tau_re, tau_im);      // rhs = w -> tau
        // T(z) = sum_{i=0}^{62} tau_i z^{63-i} = z * P(z); P, P' by Horner
        C2 pp = { rdlane(tau_re, 0), rdlane(tau_im, 0) };
        C2 dd = {0,0};
        for (int i = 1; i <= 62; ++i) {
            const C2 ti = { rdlane(tau_re, i), rdlane(tau_im, i) };
            dd = cadd(cmul(dd, g), pp);
            pp = cadd(cmul(pp, g), ti);
        }
        TgA[lane] = st2(cmul(g, pp));              // T(g)
        TpA[lane] = st2(cadd(pp, cmul(g, dd)));    // T'(g) = P + z P'
    } else if (wid == 1) {
        const C2 wl = ld2(wvA[lane]);
        float sg_re, sg_im;
        tri_solve64(wl, ld2(avA[lane]), lane, sg_re, sg_im);   // rhs = a -> sigma
        // X_0 = dB; X_{j+1} = g.*X_j + sigma_j * q
        C2 x = x0;
        for (int j = 0; j < 64; ++j) {
            Abuf[j*64 + ((lane + j) & 63)] = st2(x);
            const float sjr = rdlane(sg_re, j);
            const float sji = rdlane(sg_im, j);
            const float nr = g.re*x.re - g.im*x.im + sjr*q.re - sji*q.im;
            const float ni = g.re*x.im + g.im*x.re + sjr*q.im + sji*q.re;
            x.re = nr; x.im = ni;
        }
    } else if (wid == 2) {
        if (lane < 32) cntA[lane] = 0;
    }
    __syncthreads();   // transient smalls die here

    // ---------------- M build (all waves, rows k = 8w..8w+7, in REGISTERS) -------
    // M[k][m] = d_km g64_k + q_k r_m [ (g64_k - g64_m) + (T(g_k) - T(g_m)) ] / (g_k - g_m)
    // M[k][k] = g64_k + q_k r_k ( 64 g_k^63 + T'(g_k) )
    C2 Mk[8];
    {
        const C2 Tgm = ld2(TgA[lane]);
        const C2 Tp  = ld2(TpA[lane]);
        const C2 g63 = cmul(g64, cinv(g));
        const C2 S   = cmul(r, cadd(cscale(64.0f, g63), Tp));
        const C2 diagv = cadd(g64, cmul(q, S));    // value for M[lane][lane]
        #pragma unroll
        for (int kk = 0; kk < 8; ++kk) {
            const int k = 8*wid + kk;
            const C2 qn   = ld2(qA[k]);            // uniform reads
            const C2 g64n = ld2(g64A[k]);
            const C2 Tgn  = ld2(TgA[k]);
            const C2 num  = cmul(r, cadd(csub(g64n, g64), csub(Tgn, Tgm)));
            const C2 off  = cmul(cmul(qn, num), idmk[kk]);   // kk compile-time
            const bool isd = (lane == k);
            Mk[kk].re = isd ? diagv.re : off.re;
            Mk[kk].im = isd ? diagv.im : off.im;
        }
    }
    __syncthreads();   // M regs + counters + Cs[0] visible; cbufAll region now free

    // ---------------- replicated-reduce chain: 31 steps, ONE sync point/step ------
    {
        float2* cb = cbufAll + wid*64;             // per-wave PRIVATE broadcast buffer
        const float4* cb4 = (const float4*)cb;
        volatile int* vcnt = (volatile int*)cntA;
        cb[lane] = st2(Cv);                        // step input C_0 = C
        for (int i = 1; i < 32; ++i) {
            const int buf = i & 1;
            // produce: this wave's 8-row slice of C_{i-1} . M (reads OWN cb)
            const float4 ya = cb4[4*wid + 0];      // c_{8w},   c_{8w+1}
            const float4 yb = cb4[4*wid + 1];      // c_{8w+2}, c_{8w+3}
            const float4 yc = cb4[4*wid + 2];
            const float4 yd = cb4[4*wid + 3];
            float ar = 0.0f, ai = 0.0f;
            ar += ya.x*Mk[0].re - ya.y*Mk[0].im;  ai += ya.x*Mk[0].im + ya.y*Mk[0].re;
            ar += ya.z*Mk[1].re - ya.w*Mk[1].im;  ai += ya.z*Mk[1].im + ya.w*Mk[1].re;
            ar += yb.x*Mk[2].re - yb.y*Mk[2].im;  ai += yb.x*Mk[2].im + yb.y*Mk[2].re;
            ar += yb.z*Mk[3].re - yb.w*Mk[3].im;  ai += yb.z*Mk[3].im + yb.w*Mk[3].re;
            ar += yc.x*Mk[4].re - yc.y*Mk[4].im;  ai += yc.x*Mk[4].im + yc.y*Mk[4].re;
            ar += yc.z*Mk[5].re - yc.w*Mk[5].im;  ai += yc.z*Mk[5].im + yc.w*Mk[5].re;
            ar += yd.x*Mk[6].re - yd.y*Mk[6].im;  ai += yd.x*Mk[6].im + yd.y*Mk[6].re;
            ar += yd.z*Mk[7].re - yd.w*Mk[7].im;  ai += yd.z*Mk[7].im + yd.w*Mk[7].re;
            prtC[buf*512 + wid*64 + lane] = make_float2(ar, ai);
            __threadfence_block();                 // partial visible before counting
            if (lane == 0) atomicAdd(&cntA[i], 1);
            while (vcnt[i] < 8) { }                // all 8 partials in
            __asm__ volatile("" ::: "memory");
            // replicated reduce: every wave builds the full new vector itself
            C2 nc = {0,0};
            #pragma unroll
            for (int w2 = 0; w2 < 8; ++w2) {
                const float2 pv = prtC[buf*512 + w2*64 + lane];
                nc.re += pv.x; nc.im += pv.y;
            }
            cb[lane] = st2(nc);                    // own copy for next step (in-order DS)
            if (wid == 0) Cs[i*64 + lane] = st2(nc);
        }
    }
    __syncthreads();

    // ---------------- output: rows r = 4*wid + rr ----------------
    {
        float accK[4] = {0.0f, 0.0f, 0.0f, 0.0f};
        #pragma unroll 8
        for (int n = 0; n < 64; ++n) {
            const float2 xv = Abuf[lane*64 + ((n + lane) & 63)];
            #pragma unroll
            for (int rr = 0; rr < 4; ++rr) {
                const float2 cv = Cs[(4*wid + rr)*64 + n];   // uniform
                accK[rr] += cv.x*xv.x - cv.y*xv.y;
            }
        }
        float* outh = out + h * LL;
        #pragma unroll
        for (int rr = 0; rr < 4; ++rr) {
            outh[(4*wid + rr)*64 + lane] = 2.0f * accK[rr];
        }
    }
}

extern "C" void kernel_launch(void* const* d_in, const int* in_sizes, int n_in,
                              void* d_out, int out_size, void* d_ws, size_t ws_size,
                              hipStream_t stream) {
    const float* A_real = (const float*)d_in[0];
    const float* A_imag = (const float*)d_in[1];
    const float* B_real = (const float*)d_in[2];
    const float* B_imag = (const float*)d_in[3];
    const float* P_real = (const float*)d_in[4];
    const float* P_imag = (const float*)d_in[5];
    const float* C_real = (const float*)d_in[6];
    const float* C_imag = (const float*)d_in[7];
    const float* log_dt = (const float*)d_in[8];
    float* out = (float*)d_out;

    const size_t lds = 64128;
    ssm_dplr_kernel<<<256, 512, lds, stream>>>(
        A_real, A_imag, B_real, B_imag, P_real, P_imag,
        C_real, C_imag, log_dt, out);
}